// Round 7
// baseline (216.584 us; speedup 1.0000x reference)
//
#include <hip/hip_runtime.h>

// T=8, L=2e6, B=16384. Outputs (flat f32 concat): [0] indices 16M, [1] offsets 131073, [2] weights 16M.
constexpr long NA = 16000000;   // T*L
constexpr long NB = 131073;     // T*B+1
constexpr long WOFF = NA + NB;  // weights out start, element 16,131,073 (== 1 mod 4)
constexpr int  BLK = 256;
constexpr int  UNR = 8;                                   // 16B chunks per thread (128B each way)
constexpr int  CHUNKS = 4000000;                          // 16B chunks, indices region
constexpr int  CHW    = 3999999;                          // 16B chunks, weights main (after 3-elem prologue)
constexpr int  GA = (CHUNKS + BLK * UNR - 1) / (BLK * UNR);  // 1954 blocks (indices)
constexpr int  GC = (CHW    + BLK * UNR - 1) / (BLK * UNR);  // 1954 blocks (weights)
constexpr int  GB = ((int)NB + BLK - 1) / BLK;               // 513 blocks (offsets) — dispatched FIRST

// clang vector types: accepted by __builtin_nontemporal_load/store.
typedef int   v4i   __attribute__((ext_vector_type(4)));
typedef float v4f   __attribute__((ext_vector_type(4)));
// 16B access with only 4B alignment (dwordx4 needs only dword alignment).
typedef float v4f_u __attribute__((ext_vector_type(4), aligned(4)));

__global__ __launch_bounds__(BLK) void tbe_prep(
    const int* __restrict__ indices,
    const int* __restrict__ offsets,
    const float* __restrict__ weights,
    float* __restrict__ out) {
  const int bid = blockIdx.x;
  const int tid = threadIdx.x;

  if (bid < GB) {
    // ---- Output 1: combined_offsets (131,073 elems) + weights prologue/epilogue ----
    // Dispatched first so these scalar blocks don't straggle behind the grid.
    long j = (long)bid * BLK + tid;
    if (j < NB) {
      int v;
      if (j == NB - 1) {
        v = 16000000;                            // T*L sentinel
      } else {
        int t = (int)(j >> 14);                  // j / B
        int k = (int)(j & 16383);                // j % B
        v = offsets[t * 16385 + k] + t * 2000000;
      }
      out[NA + j] = (float)v;
    }
    if (bid == 0) {
      if (tid < 3)   out[WOFF + tid] = weights[tid];                 // prologue: 3 elems
      if (tid == 3)  out[WOFF + 15999999] = weights[15999999];       // epilogue: 1 elem
    }
  } else if (bid < GB + GA) {
    // ---- Output 0: indices int32 -> f32 (exact), 16B-aligned both sides ----
    // NT loads+stores: the harness poison fill leaves L2/L3 full of dirty lines;
    // allocating accesses evict-writeback and serialize (R1 regression). NT bypasses.
    const v4i* p = (const v4i*)indices;
    v4f* o = (v4f*)out;
    const int base = (bid - GB) * (BLK * UNR) + tid;
    if (base + (UNR - 1) * BLK < CHUNKS) {
      v4i a[UNR];
#pragma unroll
      for (int u = 0; u < UNR; ++u)
        a[u] = __builtin_nontemporal_load(&p[base + u * BLK]);
#pragma unroll
      for (int u = 0; u < UNR; ++u) {
        v4f r;
        r.x = (float)a[u].x; r.y = (float)a[u].y;
        r.z = (float)a[u].z; r.w = (float)a[u].w;
        __builtin_nontemporal_store(r, &o[base + u * BLK]);
      }
    } else {
      for (int u = 0; u < UNR; ++u) {
        int c = base + u * BLK;
        if (c < CHUNKS) {
          v4i a = __builtin_nontemporal_load(&p[c]);
          v4f r;
          r.x = (float)a.x; r.y = (float)a.y;
          r.z = (float)a.z; r.w = (float)a.w;
          __builtin_nontemporal_store(r, &o[c]);
        }
      }
    }
  } else {
    // ---- Output 2: weights copy. Misalignment on the LOAD side (no RMW penalty): ----
    // chunk c covers weights[3+4c..6+4c] -> out[WOFF+3+4c..] (store 16B-aligned).
    const v4f_u* p = (const v4f_u*)(weights + 3);
    v4f* o = (v4f*)(out + (WOFF + 3));
    const int base = (bid - GB - GA) * (BLK * UNR) + tid;
    if (base + (UNR - 1) * BLK < CHW) {
      v4f a[UNR];
#pragma unroll
      for (int u = 0; u < UNR; ++u)
        a[u] = __builtin_nontemporal_load(&p[base + u * BLK]);
#pragma unroll
      for (int u = 0; u < UNR; ++u)
        __builtin_nontemporal_store(a[u], &o[base + u * BLK]);
    } else {
      for (int u = 0; u < UNR; ++u) {
        int c = base + u * BLK;
        if (c < CHW) {
          v4f a = __builtin_nontemporal_load(&p[c]);
          __builtin_nontemporal_store(a, &o[c]);
        }
      }
    }
  }
}

extern "C" void kernel_launch(void* const* d_in, const int* in_sizes, int n_in,
                              void* d_out, int out_size, void* d_ws, size_t ws_size,
                              hipStream_t stream) {
  const int*   indices = (const int*)d_in[0];
  const int*   offsets = (const int*)d_in[1];
  const float* weights = (const float*)d_in[2];
  float*       out     = (float*)d_out;

  const int grid = GB + GA + GC;  // 4,421 blocks
  tbe_prep<<<dim3(grid), dim3(BLK), 0, stream>>>(indices, offsets, weights, out);
}